// Round 8
// baseline (619.429 us; speedup 1.0000x reference)
//
#include <hip/hip_runtime.h>
#include <hip/hip_bf16.h>
#include <cstdint>
#include <cstddef>

#define TPB 256
#define SCAN_CHUNK 1024

typedef short bf16x8 __attribute__((ext_vector_type(8)));
typedef float f32x4 __attribute__((ext_vector_type(4)));

__device__ __forceinline__ float sigmoidf_(float x) {
    return 1.0f / (1.0f + __expf(-x));
}
__device__ __forceinline__ unsigned short f2bf(float x) {   // RNE
    unsigned u = __float_as_uint(x);
    u += 0x7FFF + ((u >> 16) & 1);
    return (unsigned short)(u >> 16);
}
__device__ __forceinline__ float bf2f(unsigned short b) {
    return __uint_as_float(((unsigned)b) << 16);
}

// async 16B global->LDS: global src is PER-LANE, LDS dest is wave-uniform base
__device__ __forceinline__ void gld_lds16(const void* gsrc, void* ldst) {
    __builtin_amdgcn_global_load_lds(
        (const __attribute__((address_space(1))) unsigned*)gsrc,
        (__attribute__((address_space(3))) unsigned*)ldst, 16, 0, 0);
}

// ---------------------------------------------------------------- W prep
// SWZ: XOR-swizzled (for LDS staging); else linear col-major (for global reads)
template<int M, bool SWZ>
__device__ __forceinline__ void prep_w_body(const float* __restrict__ W,
                                            unsigned short* __restrict__ Wt, int c) {
    if (c >= M * 16) return;
    int m = c >> 4, k0 = (c & 15) << 3;
    unsigned o[4];
    #pragma unroll
    for (int j = 0; j < 4; ++j) {
        unsigned lo = f2bf(W[(size_t)(k0 + 2 * j) * M + m]);
        unsigned hi = f2bf(W[(size_t)(k0 + 2 * j + 1) * M + m]);
        o[j] = lo | (hi << 16);
    }
    unsigned byte = (unsigned)c * 16;
    if (SWZ) byte ^= (unsigned)((m & 7) << 4);
    *(uint4*)((char*)Wt + byte) = *(uint4*)o;
}

// prep fat kernel: zero counts + convert all 4 weights
__global__ __launch_bounds__(TPB) void k_prep(const float* W1, unsigned short* wt1,
                                              const float* W2, unsigned short* wt2,
                                              const float* E1, unsigned short* wtE1,
                                              const float* E2, unsigned short* wtE2,
                                              unsigned* counts, int n, int nbZ) {
    int bid = blockIdx.x;
    if (bid < nbZ) {
        int i = bid * TPB + threadIdx.x;
        if (i < n) counts[i] = 0u;
    } else {
        int t = bid - nbZ;
        if (t < 8)       prep_w_body<128, false>(W1, wt1, t * TPB + threadIdx.x);  // linear
        else if (t < 12) prep_w_body<64, true>(W2, wt2, (t - 8) * TPB + threadIdx.x);
        else if (t < 20) prep_w_body<128, true>(E1, wtE1, (t - 12) * TPB + threadIdx.x);
        else             prep_w_body<128, true>(E2, wtE2, (t - 20) * TPB + threadIdx.x);
    }
}

// ---------------------------------------------------------------- GEMM1 body
// bufA = feat(f32) @ W1; A staged in 32KB LDS (swizzled); W read from global
// (linear col-major bf16, 32KB, L1/L2-hot and shared by all blocks).
__device__ __forceinline__ void gemm1_body(const float* __restrict__ feat,
                                           const unsigned short* __restrict__ wtl,
                                           unsigned short* __restrict__ bufA,
                                           int n, int tile, unsigned short* Al) {
    const int tid = threadIdx.x;
    const int rbase = tile * 128;
    for (int ch = tid; ch < 128 * 16; ch += TPB) {
        int row = ch >> 4;
        int col8 = (ch & 15) * 8;
        int r = rbase + row;
        unsigned o4[4] = {0u, 0u, 0u, 0u};
        if (r < n) {
            float4 a = *(const float4*)(feat + (size_t)r * 128 + col8);
            float4 b = *(const float4*)(feat + (size_t)r * 128 + col8 + 4);
            o4[0] = (unsigned)f2bf(a.x) | ((unsigned)f2bf(a.y) << 16);
            o4[1] = (unsigned)f2bf(a.z) | ((unsigned)f2bf(a.w) << 16);
            o4[2] = (unsigned)f2bf(b.x) | ((unsigned)f2bf(b.y) << 16);
            o4[3] = (unsigned)f2bf(b.z) | ((unsigned)f2bf(b.w) << 16);
        }
        unsigned byte = ((unsigned)ch * 16) ^ (unsigned)((row & 7) << 4);
        *(uint4*)((char*)Al + byte) = *(uint4*)o4;
    }
    __syncthreads();

    const int wv = tid >> 6, ln = tid & 63, lr = ln & 15, lg = ln >> 4;
    f32x4 acc[2][8];
    #pragma unroll
    for (int i = 0; i < 2; ++i)
        #pragma unroll
        for (int j = 0; j < 8; ++j) acc[i][j] = (f32x4){0.f, 0.f, 0.f, 0.f};

    #pragma unroll
    for (int kk = 0; kk < 4; ++kk) {
        const int kb = kk * 64 + lg * 16;
        bf16x8 af[2];
        #pragma unroll
        for (int rf = 0; rf < 2; ++rf) {
            int row = wv * 32 + rf * 16 + lr;
            unsigned byte = (unsigned)(row * 256 + kb) ^ (unsigned)((row & 7) << 4);
            af[rf] = *(bf16x8*)((char*)Al + byte);
        }
        #pragma unroll
        for (int mf = 0; mf < 8; ++mf) {
            int col = mf * 16 + lr;
            bf16x8 bfg = *(const bf16x8*)((const char*)wtl + col * 256 + kb);
            acc[0][mf] = __builtin_amdgcn_mfma_f32_16x16x32_bf16(af[0], bfg, acc[0][mf], 0, 0, 0);
            acc[1][mf] = __builtin_amdgcn_mfma_f32_16x16x32_bf16(af[1], bfg, acc[1][mf], 0, 0, 0);
        }
    }
    #pragma unroll
    for (int rf = 0; rf < 2; ++rf) {
        #pragma unroll
        for (int j = 0; j < 4; ++j) {
            int row = rbase + wv * 32 + rf * 16 + lg * 4 + j;
            if (row < n) {
                #pragma unroll
                for (int mf = 0; mf < 8; ++mf) {
                    int col = mf * 16 + lr;
                    bufA[(size_t)row * 128 + col] = f2bf(acc[rf][mf][j]);
                }
            }
        }
    }
}

// gdv SIMT GEMM body (K=73, M=32, 32 rows/block)
__device__ __forceinline__ void gemm_s_body(const float* __restrict__ A,
                                            const float* __restrict__ W,
                                            const float* __restrict__ bias,
                                            unsigned short* __restrict__ C,
                                            int n, int tile,
                                            float* Alds, float* Wlds) {
    for (int i = threadIdx.x; i < 73 * 32; i += TPB) Wlds[i] = W[i];
    const int c0 = threadIdx.x & 31;
    const int rg = threadIdx.x >> 5;
    const int rbase = tile * 32;
    for (int i = threadIdx.x; i < 32 * 73; i += TPB) {
        int rr = i / 73;
        int r = rbase + rr;
        Alds[i] = (r < n) ? A[(size_t)r * 73 + (i - rr * 73)] : 0.0f;
    }
    __syncthreads();
    float acc[4] = {0.f, 0.f, 0.f, 0.f};
    const float* Ab = &Alds[rg * 4 * 73];
    #pragma unroll 4
    for (int k = 0; k < 73; ++k) {
        float wv = Wlds[k * 32 + c0];
        #pragma unroll
        for (int j = 0; j < 4; ++j) acc[j] += Ab[j * 73 + k] * wv;
    }
    #pragma unroll
    for (int j = 0; j < 4; ++j) {
        int r = rbase + rg * 4 + j;
        if (r < n) C[(size_t)r * 128 + 64 + c0] = f2bf(sigmoidf_(acc[j] + bias[c0]));
    }
}

// front fat kernel: pass1 atomics ∥ GEMM1 ∥ gdv GEMM ∥ pr
__global__ __launch_bounds__(TPB) void k_front(
        const int* __restrict__ dst, unsigned* __restrict__ counts,
        unsigned* __restrict__ epos, int E,
        const float* __restrict__ feat, const unsigned short* __restrict__ wtl1,
        unsigned short* __restrict__ bufA,
        const float* __restrict__ gdv, const float* __restrict__ gdvW,
        const float* __restrict__ gdvB,
        const float* __restrict__ pr, const float* __restrict__ prW,
        const float* __restrict__ prB,
        unsigned short* __restrict__ enc, int n, int nbE, int nbM, int nG) {
    __shared__ __align__(16) char smem[32768];
    int bid = blockIdx.x;
    if (bid < nbE) {
        int e = bid * TPB + threadIdx.x;
        if (e < E) epos[e] = atomicAdd(&counts[dst[e]], 1u);
    } else if (bid < nbE + nbM) {
        gemm1_body(feat, wtl1, bufA, n, bid - nbE, (unsigned short*)smem);
    } else if (bid < nbE + nbM + nG) {
        gemm_s_body(gdv, gdvW, gdvB, enc, n, bid - nbE - nbM,
                    (float*)smem, (float*)(smem + 9344));
    } else {
        int i = (bid - nbE - nbM - nG) * TPB + threadIdx.x;
        if (i < n * 32) {
            int node = i >> 5;
            int c = i & 31;
            float v = pr[node] * prW[c] + prB[c];
            enc[(size_t)node * 128 + 96 + c] = f2bf(sigmoidf_(v));
        }
    }
}

// ---------------------------------------------------------------- scan chain

__global__ __launch_bounds__(TPB) void k_scan_a(const unsigned* __restrict__ counts,
                                                int* __restrict__ rowptr,
                                                int* __restrict__ bsums, int n) {
    __shared__ int s[SCAN_CHUNK];
    int base = blockIdx.x * SCAN_CHUNK;
    int orig[4];
    #pragma unroll
    for (int j0 = 0; j0 < 4; ++j0) {
        int j = threadIdx.x + j0 * TPB;
        int v = (base + j < n) ? (int)counts[base + j] : 0;
        orig[j0] = v;
        s[j] = v;
    }
    __syncthreads();
    for (int off = 1; off < SCAN_CHUNK; off <<= 1) {
        int t[4];
        #pragma unroll
        for (int j0 = 0; j0 < 4; ++j0) {
            int j = threadIdx.x + j0 * TPB;
            t[j0] = (j >= off) ? s[j - off] : 0;
        }
        __syncthreads();
        #pragma unroll
        for (int j0 = 0; j0 < 4; ++j0) {
            int j = threadIdx.x + j0 * TPB;
            s[j] += t[j0];
        }
        __syncthreads();
    }
    #pragma unroll
    for (int j0 = 0; j0 < 4; ++j0) {
        int j = threadIdx.x + j0 * TPB;
        if (base + j < n) rowptr[base + j] = s[j] - orig[j0];
    }
    if (threadIdx.x == 0) bsums[blockIdx.x] = s[SCAN_CHUNK - 1];
}

// merged scan_b+c: each block scans bsums (<=128) locally, then offsets rowptr
__global__ __launch_bounds__(TPB) void k_scan_c(int* __restrict__ rowptr,
                                                const int* __restrict__ bsums,
                                                int n, int E, int nb) {
    __shared__ int sb[128];
    int t = threadIdx.x;
    if (t < 128) sb[t] = (t < nb) ? bsums[t] : 0;
    __syncthreads();
    for (int off = 1; off < 128; off <<= 1) {
        int x = 0;
        if (t < 128 && t >= off) x = sb[t - off];
        __syncthreads();
        if (t < 128) sb[t] += x;     // inclusive
        __syncthreads();
    }
    int i = blockIdx.x * TPB + t;
    if (i < n) {
        int chunk = i >> 10;         // SCAN_CHUNK = 1024
        int prefix = (chunk == 0) ? 0 : sb[chunk - 1];
        rowptr[i] += prefix;
    }
    if (i == 0) rowptr[n] = E;
}

// atomic-free fill: ONE packed 8B scatter per edge {src, raw ew}
__global__ __launch_bounds__(TPB) void k_fill(const int* __restrict__ src,
                                              const int* __restrict__ dst,
                                              const float* __restrict__ ew,
                                              const int* __restrict__ rowptr,
                                              const unsigned* __restrict__ epos,
                                              uint2* __restrict__ edges, int E) {
    int e = blockIdx.x * TPB + threadIdx.x;
    if (e < E) {
        unsigned slot = (unsigned)rowptr[dst[e]] + epos[e];
        uint2 pk;
        pk.x = (unsigned)src[e];
        pk.y = __float_as_uint(ew[e]);
        edges[slot] = pk;
    }
}

// deg = 1 + row sum of raw weights; dinv = rsqrt
__global__ __launch_bounds__(TPB) void k_deg(const int* __restrict__ rowptr,
                                             const uint2* __restrict__ edges,
                                             float* __restrict__ dinv, int n) {
    int i = blockIdx.x * TPB + threadIdx.x;
    if (i >= n) return;
    int beg = rowptr[i], end = rowptr[i + 1];
    float s = 1.0f;
    for (int e = beg; e < end; ++e) s += __uint_as_float(edges[e].y);
    dinv[i] = rsqrtf(s);
}

// ---------------------------------------------------------------- aggregation
// agg128: D=128, tanh; computes nv = ew*dinv_src and WRITES IT BACK into
// edges[].y (lane 0) so agg64 skips the dinv gather stream entirely.
__global__ __launch_bounds__(TPB) void k_agg128(const unsigned short* __restrict__ h,
                                                const int* __restrict__ rowptr,
                                                uint2* __restrict__ edges,
                                                const float* __restrict__ dinv,
                                                const float* __restrict__ bias,
                                                unsigned short* __restrict__ out, int n) {
    const int lane = threadIdx.x & 63;
    const int node = blockIdx.x * 4 + (threadIdx.x >> 6);
    if (node >= n) return;
    float acc0, acc1;
    const float di = dinv[node];
    {
        unsigned hv = *(const unsigned*)&h[(size_t)node * 128 + lane * 2];
        acc0 = bf2f((unsigned short)hv) * di;
        acc1 = bf2f((unsigned short)(hv >> 16)) * di;
    }
    const int beg = rowptr[node];
    const int end = rowptr[node + 1];
    for (int e = beg; e < end; e += 8) {
        int ss[8]; float nn[8];
        #pragma unroll
        for (int u = 0; u < 8; ++u) {
            int idx = e + u;
            int cl = idx < end ? idx : (end - 1);
            uint2 ed = edges[cl];                    // wave-uniform 8B load
            ss[u] = (int)ed.x;
            nn[u] = (idx < end) ? __uint_as_float(ed.y) * dinv[ss[u]] : 0.0f;
        }
        if (lane == 0) {
            #pragma unroll
            for (int u = 0; u < 8; ++u)
                if (e + u < end) edges[e + u].y = __float_as_uint(nn[u]);
        }
        unsigned hv[8];
        #pragma unroll
        for (int u = 0; u < 8; ++u)
            hv[u] = *(const unsigned*)&h[(size_t)ss[u] * 128 + lane * 2];
        #pragma unroll
        for (int u = 0; u < 8; ++u) {
            acc0 += bf2f((unsigned short)hv[u]) * nn[u];
            acc1 += bf2f((unsigned short)(hv[u] >> 16)) * nn[u];
        }
    }
    float v0 = tanhf(acc0 * di + bias[lane * 2]);
    float v1 = tanhf(acc1 * di + bias[lane * 2 + 1]);
    unsigned pk = (unsigned)f2bf(v0) | ((unsigned)f2bf(v1) << 16);
    *(unsigned*)&out[(size_t)node * 128 + lane * 2] = pk;
}

// agg64: D=64, sigmoid; edges[].y is PRE-SCALED nv -> only 2 request streams
__global__ __launch_bounds__(TPB) void k_agg64(const unsigned short* __restrict__ h,
                                               const int* __restrict__ rowptr,
                                               const uint2* __restrict__ edges,
                                               const float* __restrict__ dinv,
                                               const float* __restrict__ bias,
                                               unsigned short* __restrict__ enc, int n) {
    const int lane = threadIdx.x & 63;
    const int node = blockIdx.x * 4 + (threadIdx.x >> 6);
    if (node >= n) return;
    const float di = dinv[node];
    float acc = bf2f(h[(size_t)node * 64 + lane]) * di;
    const int beg = rowptr[node];
    const int end = rowptr[node + 1];
    for (int e = beg; e < end; e += 8) {
        int ss[8]; float nn[8];
        #pragma unroll
        for (int u = 0; u < 8; ++u) {
            int idx = e + u;
            int cl = idx < end ? idx : (end - 1);
            uint2 ed = edges[cl];
            ss[u] = (int)ed.x;
            nn[u] = (idx < end) ? __uint_as_float(ed.y) : 0.0f;   // pre-scaled
        }
        unsigned short hv[8];
        #pragma unroll
        for (int u = 0; u < 8; ++u) hv[u] = h[(size_t)ss[u] * 64 + lane];
        #pragma unroll
        for (int u = 0; u < 8; ++u) acc += bf2f(hv[u]) * nn[u];
    }
    float v = sigmoidf_(acc * di + bias[lane]);
    enc[(size_t)node * 128 + lane] = f2bf(v);
}

// ---------------------------------------------------------------- MFMA GEMM (LDS W)
template<int M, int ACT, bool A_BF16, bool OUT_F32>
__device__ __forceinline__ void mgemm_body(const void* __restrict__ Ap,
                                           const unsigned short* __restrict__ Wtg,
                                           const float* __restrict__ bias,
                                           void* __restrict__ Cp, int ldc, int coff,
                                           int n, int tile,
                                           unsigned short* Al, unsigned short* Wt) {
    const int tid = threadIdx.x;
    const int wv = tid >> 6;
    const int ln = tid & 63;
    const int rbase = tile * 128;

    constexpr int WCH = (M * 128 * 2) / 1024;
    #pragma unroll
    for (int c = 0; c < WCH / 4; ++c) {
        int cc = wv * (WCH / 4) + c;
        gld_lds16((const char*)Wtg + cc * 1024 + ln * 16, (char*)Wt + cc * 1024);
    }
    if (A_BF16 && rbase + 128 <= n) {
        #pragma unroll
        for (int it = 0; it < 8; ++it) {
            unsigned dbase = (unsigned)(wv * 8 + it) * 1024;
            unsigned d = dbase + (unsigned)ln * 16;
            unsigned row = d >> 8;
            unsigned s = d ^ ((row & 7) << 4);
            gld_lds16((const char*)Ap + (size_t)rbase * 256 + s, (char*)Al + dbase);
        }
    } else {
        for (int ch = tid; ch < 128 * 16; ch += TPB) {
            int row = ch >> 4;
            int col8 = (ch & 15) * 8;
            int r = rbase + row;
            unsigned o4[4] = {0u, 0u, 0u, 0u};
            if (r < n) {
                uint4 v = *(const uint4*)((const unsigned short*)Ap + (size_t)r * 128 + col8);
                o4[0] = v.x; o4[1] = v.y; o4[2] = v.z; o4[3] = v.w;
            }
            unsigned byte = ((unsigned)ch * 16) ^ (unsigned)((row & 7) << 4);
            *(uint4*)((char*)Al + byte) = *(uint4*)o4;
        }
    }
    __syncthreads();

    const int lr = ln & 15;
    const int lg = ln >> 4;
    constexpr int MF = M / 16;
    f32x4 acc[2][MF];
    #pragma unroll
    for (int i = 0; i < 2; ++i)
        #pragma unroll
        for (int j = 0; j < MF; ++j) acc[i][j] = (f32x4){0.f, 0.f, 0.f, 0.f};

    #pragma unroll
    for (int kk = 0; kk < 4; ++kk) {
        const int kb = kk * 64 + lg * 16;
        bf16x8 af[2];
        #pragma unroll
        for (int rf = 0; rf < 2; ++rf) {
            int row = wv * 32 + rf * 16 + lr;
            unsigned byte = (unsigned)(row * 256 + kb) ^ (unsigned)((row & 7) << 4);
            af[rf] = *(bf16x8*)((char*)Al + byte);
        }
        #pragma unroll
        for (int mf = 0; mf < MF; ++mf) {
            int col = mf * 16 + lr;
            unsigned byte = (unsigned)(col * 256 + kb) ^ (unsigned)((col & 7) << 4);
            bf16x8 bfg = *(bf16x8*)((char*)Wt + byte);
            acc[0][mf] = __builtin_amdgcn_mfma_f32_16x16x32_bf16(af[0], bfg, acc[0][mf], 0, 0, 0);
            acc[1][mf] = __builtin_amdgcn_mfma_f32_16x16x32_bf16(af[1], bfg, acc[1][mf], 0, 0, 0);
        }
    }
    #pragma unroll
    for (int rf = 0; rf < 2; ++rf) {
        #pragma unroll
        for (int j = 0; j < 4; ++j) {
            int row = rbase + wv * 32 + rf * 16 + lg * 4 + j;
            if (row < n) {
                #pragma unroll
                for (int mf = 0; mf < MF; ++mf) {
                    int col = mf * 16 + lr;
                    float v = acc[rf][mf][j] + (bias ? bias[col] : 0.0f);
                    if constexpr (ACT == 1) v = tanhf(v);
                    else if constexpr (ACT == 2) v = sigmoidf_(v);
                    if constexpr (OUT_F32)
                        ((float*)Cp)[(size_t)row * ldc + coff + col] = v;
                    else
                        ((unsigned short*)Cp)[(size_t)row * ldc + coff + col] = f2bf(v);
                }
            }
        }
    }
}

__global__ __launch_bounds__(TPB) void k_mgemm64(const unsigned short* __restrict__ Ap,
                                                 const unsigned short* __restrict__ Wtg,
                                                 unsigned short* __restrict__ Cp, int n) {
    __shared__ __align__(16) unsigned short Al[128 * 128];
    __shared__ __align__(16) unsigned short Wt[64 * 128];
    mgemm_body<64, 0, true, false>(Ap, Wtg, nullptr, Cp, 64, 0, n, blockIdx.x, Al, Wt);
}

// fused encoder: out = tanh(enc@eW1+b1) @ eW2 + b2  (intermediate in LDS)
__global__ __launch_bounds__(TPB) void k_enc2(const unsigned short* __restrict__ enc,
                                              const unsigned short* __restrict__ w1g,
                                              const float* __restrict__ b1,
                                              const unsigned short* __restrict__ w2g,
                                              const float* __restrict__ b2,
                                              float* __restrict__ out, int n) {
    __shared__ __align__(16) unsigned short Al[128 * 128];
    __shared__ __align__(16) unsigned short Wt[128 * 128];
    const int tid = threadIdx.x;
    const int wv = tid >> 6;
    const int ln = tid & 63;
    const int rbase = blockIdx.x * 128;
    const int lr = ln & 15;
    const int lg = ln >> 4;

    #pragma unroll
    for (int c = 0; c < 8; ++c) {
        int cc = wv * 8 + c;
        gld_lds16((const char*)w1g + cc * 1024 + ln * 16, (char*)Wt + cc * 1024);
    }
    if (rbase + 128 <= n) {
        #pragma unroll
        for (int it = 0; it < 8; ++it) {
            unsigned dbase = (unsigned)(wv * 8 + it) * 1024;
            unsigned d = dbase + (unsigned)ln * 16;
            unsigned row = d >> 8;
            unsigned s = d ^ ((row & 7) << 4);
            gld_lds16((const char*)enc + (size_t)rbase * 256 + s, (char*)Al + dbase);
        }
    } else {
        for (int ch = tid; ch < 128 * 16; ch += TPB) {
            int row = ch >> 4;
            int col8 = (ch & 15) * 8;
            int r = rbase + row;
            unsigned o4[4] = {0u, 0u, 0u, 0u};
            if (r < n) {
                uint4 v = *(const uint4*)(enc + (size_t)r * 128 + col8);
                o4[0] = v.x; o4[1] = v.y; o4[2] = v.z; o4[3] = v.w;
            }
            unsigned byte = ((unsigned)ch * 16) ^ (unsigned)((row & 7) << 4);
            *(uint4*)((char*)Al + byte) = *(uint4*)o4;
        }
    }
    __syncthreads();

    f32x4 acc[2][8];
    #pragma unroll
    for (int i = 0; i < 2; ++i)
        #pragma unroll
        for (int j = 0; j < 8; ++j) acc[i][j] = (f32x4){0.f, 0.f, 0.f, 0.f};
    #pragma unroll
    for (int kk = 0; kk < 4; ++kk) {
        const int kb = kk * 64 + lg * 16;
        bf16x8 af[2];
        #pragma unroll
        for (int rf = 0; rf < 2; ++rf) {
            int row = wv * 32 + rf * 16 + lr;
            unsigned byte = (unsigned)(row * 256 + kb) ^ (unsigned)((row & 7) << 4);
            af[rf] = *(bf16x8*)((char*)Al + byte);
        }
        #pragma unroll
        for (int mf = 0; mf < 8; ++mf) {
            int col = mf * 16 + lr;
            unsigned byte = (unsigned)(col * 256 + kb) ^ (unsigned)((col & 7) << 4);
            bf16x8 bfg = *(bf16x8*)((char*)Wt + byte);
            acc[0][mf] = __builtin_amdgcn_mfma_f32_16x16x32_bf16(af[0], bfg, acc[0][mf], 0, 0, 0);
            acc[1][mf] = __builtin_amdgcn_mfma_f32_16x16x32_bf16(af[1], bfg, acc[1][mf], 0, 0, 0);
        }
    }
    __syncthreads();

    #pragma unroll
    for (int c = 0; c < 8; ++c) {
        int cc = wv * 8 + c;
        gld_lds16((const char*)w2g + cc * 1024 + ln * 16, (char*)Wt + cc * 1024);
    }
    #pragma unroll
    for (int rf = 0; rf < 2; ++rf) {
        #pragma unroll
        for (int j = 0; j < 4; ++j) {
            int rl = wv * 32 + rf * 16 + lg * 4 + j;
            #pragma unroll
            for (int mf = 0; mf < 8; ++mf) {
                int col = mf * 16 + lr;
                float v = tanhf(acc[rf][mf][j] + b1[col]);
                unsigned byte = (unsigned)(rl * 256 + col * 2) ^ (unsigned)((rl & 7) << 4);
                *(unsigned short*)((char*)Al + byte) = f2bf(v);
            }
        }
    }
    __syncthreads();

    #pragma unroll
    for (int i = 0; i < 2; ++i)
        #pragma unroll
        for (int j = 0; j < 8; ++j) acc[i][j] = (f32x4){0.f, 0.f, 0.f, 0.f};
    #pragma unroll
    for (int kk = 0; kk < 4; ++kk) {
        const int kb = kk * 64 + lg * 16;
        bf16x8 af[2];
        #pragma unroll
        for (int rf = 0; rf < 2; ++rf) {
            int row = wv * 32 + rf * 16 + lr;
            unsigned byte = (unsigned)(row * 256 + kb) ^ (unsigned)((row & 7) << 4);
            af[rf] = *(bf16x8*)((char*)Al + byte);
        }
        #pragma unroll
        for (int mf = 0; mf < 8; ++mf) {
            int col = mf * 16 + lr;
            unsigned byte = (unsigned)(col * 256 + kb) ^ (unsigned)((col & 7) << 4);
            bf16x8 bfg = *(bf16x8*)((char*)Wt + byte);
            acc[0][mf] = __builtin_amdgcn_mfma_f32_16x16x32_bf16(af[0], bfg, acc[0][mf], 0, 0, 0);
            acc[1][mf] = __builtin_amdgcn_mfma_f32_16x16x32_bf16(af[1], bfg, acc[1][mf], 0, 0, 0);
        }
    }
    #pragma unroll
    for (int rf = 0; rf < 2; ++rf) {
        #pragma unroll
        for (int j = 0; j < 4; ++j) {
            int row = rbase + wv * 32 + rf * 16 + lg * 4 + j;
            if (row < n) {
                #pragma unroll
                for (int mf = 0; mf < 8; ++mf) {
                    int col = mf * 16 + lr;
                    out[(size_t)row * 128 + col] = acc[rf][mf][j] + b2[col];
                }
            }
        }
    }
}

// ---------------------------------------------------------------- launch

extern "C" void kernel_launch(void* const* d_in, const int* in_sizes, int n_in,
                              void* d_out, int out_size, void* d_ws, size_t ws_size,
                              hipStream_t stream) {
    const float* feat = (const float*)d_in[0];
    const float* gdv  = (const float*)d_in[1];
    const float* pr   = (const float*)d_in[2];
    const int*   eidx = (const int*)d_in[3];
    const float* ew   = (const float*)d_in[4];
    const float* W1   = (const float*)d_in[5];
    const float* b1   = (const float*)d_in[6];
    const float* W2   = (const float*)d_in[7];
    const float* b2   = (const float*)d_in[8];
    const float* gdvW = (const float*)d_in[9];
    const float* gdvB = (const float*)d_in[10];
    const float* prW  = (const float*)d_in[11];
    const float* prB  = (const float*)d_in[12];
    const float* eW1  = (const float*)d_in[13];
    const float* eB1  = (const float*)d_in[14];
    const float* eW2  = (const float*)d_in[15];
    const float* eB2  = (const float*)d_in[16];
    float* out = (float*)d_out;

    const int N = in_sizes[0] / 128;
    const int E = in_sizes[4];
    const int* srcA = eidx;
    const int* dstA = eidx + E;

    char* p = (char*)d_ws;
    auto alloc = [&](size_t bytes) {
        char* r = p;
        p += (bytes + 255) & ~(size_t)255;
        return r;
    };
    unsigned* counts = (unsigned*)alloc((size_t)N * 4);
    unsigned* epos   = (unsigned*)alloc((size_t)E * 4);
    float*    dinv   = (float*)   alloc((size_t)N * 4);
    int*      rowptr = (int*)     alloc((size_t)(N + 1) * 4);
    int*      bsums  = (int*)     alloc(256 * 4);
    uint2*    edges  = (uint2*)   alloc((size_t)E * 8);
    unsigned short* wt1  = (unsigned short*)alloc(128 * 128 * 2);   // LINEAR col-major
    unsigned short* wt2  = (unsigned short*)alloc(128 * 64 * 2);    // swizzled
    unsigned short* wtE1 = (unsigned short*)alloc(128 * 128 * 2);   // swizzled
    unsigned short* wtE2 = (unsigned short*)alloc(128 * 128 * 2);   // swizzled
    unsigned short* bufA = (unsigned short*)alloc((size_t)N * 128 * 2);  // h -> h2
    unsigned short* bufB = (unsigned short*)alloc((size_t)N * 128 * 2);  // enc
    unsigned short* bufC = (unsigned short*)alloc((size_t)N * 128 * 2);  // h1

    const int nbN = (N + TPB - 1) / TPB;
    const int nbE = (E + TPB - 1) / TPB;
    const int nscan = (N + SCAN_CHUNK - 1) / SCAN_CHUNK;
    const int nbM = (N + 127) / 128;
    const int nA = (N + 3) / 4;
    const int nG = (N + 31) / 32;
    const int nP = (N * 32 + TPB - 1) / TPB;

    // prep: zero counts + convert weights
    k_prep<<<nbN + 28, TPB, 0, stream>>>(W1, wt1, W2, wt2, eW1, wtE1, eW2, wtE2,
                                         counts, N, nbN);
    // pass1 ∥ GEMM1 ∥ gdv ∥ pr
    k_front<<<nbE + nbM + nG + nP, TPB, 0, stream>>>(
        dstA, counts, epos, E, feat, wt1, bufA,
        gdv, gdvW, gdvB, pr, prW, prB, bufB, N, nbE, nbM, nG);
    k_scan_a<<<nscan, TPB, 0, stream>>>(counts, rowptr, bsums, N);
    k_scan_c<<<nbN, TPB, 0, stream>>>(rowptr, bsums, N, E, nscan);
    k_fill<<<nbE, TPB, 0, stream>>>(srcA, dstA, ew, rowptr, epos, edges, E);
    k_deg<<<nbN, TPB, 0, stream>>>(rowptr, edges, dinv, N);
    // h1 = tanh(agg(h)+b1) -> bufC ; writes scaled nv back into edges
    k_agg128<<<nA, TPB, 0, stream>>>(bufA, rowptr, edges, dinv, b1, bufC, N);
    // h2 = h1 @ W2 -> bufA (ld 64)
    k_mgemm64<<<nbM, TPB, 0, stream>>>(bufC, wt2, bufA, N);
    // enc[:,0:64] = sigmoid(agg(h2)+b2)
    k_agg64<<<nA, TPB, 0, stream>>>(bufA, rowptr, edges, dinv, b2, bufB, N);
    // out = tanh(enc@eW1+eB1)@eW2 + eB2   (f32)
    k_enc2<<<nbM, TPB, 0, stream>>>(bufB, wtE1, eB1, wtE2, eB2, out, N);
}